// Round 8
// baseline (1939.310 us; speedup 1.0000x reference)
//
#include <hip/hip_runtime.h>

// BiLSTM + partial-CRF loss, MI355X (gfx950).
// R8: FLAG-FREE sync -- sequencing embedded in the h data. Producer forces
// each stored bf16's LSB to (it&1); consumers agent-load h and retry until
// all LSBs == (it-1)&1. k_fill pre-writes every H2 block with the opposite
// parity of its (unique) writing step, so poison/stale can never false-
// accept. Removes the vmcnt-drain + flag-propagate + detect hops of R7's
// protocol (3 MALL RTs -> ~1). Keeps R7's validated structure: K-split
// across waves, blocked H2, ds_write_b128 LDS partial sums.
//
// Sizes: B=64, L=512, V=50000, E=256, H=512, T=32.
// Workspace (~84 MiB):
//   x2   bf16 [512*64][256]                16777216 B @ 0
//   H2   bf16 blocked [t][d][g][s][256]    67108864 B @ 16777216
//   em   f32  [512*64][32]                  4194304 B @ 83886080

#define IMPOSSIBLE -10000.0f

typedef __attribute__((ext_vector_type(8))) short bf16x8;
typedef __attribute__((ext_vector_type(4))) float f32x4;
typedef unsigned int u32;
typedef unsigned short u16;
typedef unsigned long long u64;

__device__ __forceinline__ u16 f2b(float f) {           // fp32 -> bf16 (RNE)
  union { float f; u32 u; } v; v.f = f;
  return (u16)((v.u + 0x7fffu + ((v.u >> 16) & 1u)) >> 16);
}
__device__ __forceinline__ float sigm(float x) { return 1.0f / (1.0f + __expf(-x)); }
__device__ __forceinline__ float tanh_f(float x) { return 1.0f - 2.0f / (__expf(2.0f * x) + 1.0f); }

// ---------------------------------------------------------------------------
__global__ void k_init(float* __restrict__ out) {
  if (threadIdx.x == 0)
    __hip_atomic_store((u32*)out, 0u, __ATOMIC_RELAXED, __HIP_MEMORY_SCOPE_AGENT);
}

// ---------------------------------------------------------------------------
// Prefill H2 with anti-parity: block (t,d) is written by k_lstm at step
// it=(d?511-t:t) with LSB=it&1; prefill LSB = (t+d+1)&1 = 1-(it&1).
// Agent-scope stores: no dirty L2 lines that could later clobber MALL.
__global__ __launch_bounds__(256) void k_fill(u64* __restrict__ H2q) {
  const size_t i0 = ((size_t)blockIdx.x * 256 + threadIdx.x) * 4;  // u64 index
  const int t = (int)(i0 >> 14);            // 16384 u64 per t
  const int d = (int)((i0 >> 13) & 1);
  const u64 val = ((t + d + 1) & 1) ? 0x0001000100010001ull : 0ull;
#pragma unroll
  for (int k = 0; k < 4; ++k)
    __hip_atomic_store(H2q + i0 + k, val, __ATOMIC_RELAXED, __HIP_MEMORY_SCOPE_AGENT);
}

// ---------------------------------------------------------------------------
// x2[t*64+b][e] = bf16(emb[sents[b][t]][e]).  One block per t.
__global__ __launch_bounds__(256) void k_embed(
    const int* __restrict__ sents, const float* __restrict__ emb,
    u16* __restrict__ x2) {
  __shared__ int tok[64];
  const int tid = threadIdx.x, t = blockIdx.x;
  if (tid < 64) tok[tid] = sents[tid * 512 + t];
  __syncthreads();
#pragma unroll
  for (int i = 0; i < 16; ++i) {
    const int v = i * 256 + tid;          // float4 index
    const int row = v >> 6, ke = (v & 63) * 4;
    const float4 f = *(const float4*)(emb + (size_t)tok[row] * 256 + ke);
    ushort4 s; s.x = f2b(f.x); s.y = f2b(f.y); s.z = f2b(f.z); s.w = f2b(f.w);
    *(ushort4*)&x2[((size_t)t * 64 + row) * 256 + ke] = s;
  }
}

// ---------------------------------------------------------------------------
// Persistent BiLSTM. 256 wgs x 256 thr, 1 wg/CU. group r=wid&7 -> (d=r>>2,
// g=r&3); slice s=wid>>3 (j0=s*16). Wave wv owns K-quarter for ALL 4 gates.
// Per step: speculatively issue 8 u64 agent h-loads + x loads -> x MFMAs
// (overlap h latency) -> parity-check h, retry until LSBs==(it-1)&1 ->
// h MFMAs -> ds_write_b128 partials -> barrier -> reduce + gates ->
// packed agent h store with LSB=it&1 (NO drain, NO flag).
__global__ __launch_bounds__(256, 1) void k_lstm(
    const float* __restrict__ Whf, const float* __restrict__ Whb,
    const float* __restrict__ Wif, const float* __restrict__ Wib,
    const float* __restrict__ bf_, const float* __restrict__ bb_,
    const u16* __restrict__ x2, u16* __restrict__ H2) {
  __shared__ float pre4[4096];          // [wv][gate][kh][lm][rr]
  const int tid = threadIdx.x, wid = blockIdx.x;
  const int r = wid & 7, d = r >> 2, g = r & 3, s = wid >> 3;
  const int b0 = g * 16, j0 = s * 16;
  const float* __restrict__ Whh = d ? Whb : Whf;
  const float* __restrict__ Wih = d ? Wib : Wif;
  const float* __restrict__ bias = d ? bb_ : bf_;
  const int wv = tid >> 6, lane = tid & 63, lm = lane & 15, kh = lane >> 4;
  const int bl = tid >> 4, jj = tid & 15;

  // ---- weight fragments: B[k][n], n=lane&15, k = kh*8+j + 32*kt + wv*Kq ----
  bf16x8 wih_f[8], whh_f[16];
#pragma unroll
  for (int gg = 0; gg < 4; ++gg) {
    const float* wp = Wih + (size_t)(gg * 512 + j0 + lm) * 256 + wv * 64;
#pragma unroll
    for (int kt = 0; kt < 2; ++kt) {
      bf16x8 f;
#pragma unroll
      for (int j = 0; j < 8; ++j) f[j] = (short)f2b(wp[kt * 32 + kh * 8 + j]);
      wih_f[gg * 2 + kt] = f;
    }
    const float* wq = Whh + (size_t)(gg * 512 + j0 + lm) * 512 + wv * 128;
#pragma unroll
    for (int kt = 0; kt < 4; ++kt) {
      bf16x8 f;
#pragma unroll
      for (int j = 0; j < 8; ++j) f[j] = (short)f2b(wq[kt * 32 + kh * 8 + j]);
      whh_f[gg * 4 + kt] = f;
    }
  }
  const float b_i = bias[0 * 512 + j0 + jj];
  const float b_f = bias[1 * 512 + j0 + jj];
  const float b_g = bias[2 * 512 + j0 + jj];
  const float b_o = bias[3 * 512 + j0 + jj];

  const u64 PM = 0x0001000100010001ull;
  float c = 0.f;
  const f32x4 z = {0.f, 0.f, 0.f, 0.f};
#pragma unroll 1
  for (int it = 0; it < 512; ++it) {
    const int tt = d ? (511 - it) : it;
    // speculative h loads (agent, MALL): issue FIRST so they fly during x work
    u64 hv[8];
    const u64* hb8[8];
    if (it > 0) {
      const int tp = d ? (tt + 1) : (tt - 1);
#pragma unroll
      for (int kt = 0; kt < 4; ++kt) {
        const int sG = wv * 8 + kt * 2 + (kh >> 1);
        const u64* base = (const u64*)H2 +
            ((((size_t)tp * 2 + d) * 4 + g) * 32 + sG) * 64 + lm * 4 + (kh & 1) * 2;
        hb8[kt * 2] = base; hb8[kt * 2 + 1] = base + 1;
      }
#pragma unroll
      for (int i = 0; i < 8; ++i)
        hv[i] = __hip_atomic_load(hb8[i], __ATOMIC_RELAXED, __HIP_MEMORY_SCOPE_AGENT);
    }
    // x a-frags (K-quarter)
    bf16x8 xa[2];
    {
      const u16* xp = x2 + ((size_t)tt * 64 + b0 + lm) * 256 + wv * 64 + kh * 8;
      xa[0] = *(const bf16x8*)xp;
      xa[1] = *(const bf16x8*)(xp + 32);
    }
    f32x4 accg[4] = {z, z, z, z};
#pragma unroll
    for (int gg = 0; gg < 4; ++gg)
#pragma unroll
      for (int kt = 0; kt < 2; ++kt)
        accg[gg] = __builtin_amdgcn_mfma_f32_16x16x32_bf16(xa[kt], wih_f[gg * 2 + kt], accg[gg], 0, 0, 0);
    if (it > 0) {
      // parity gate: every bf16 must carry LSB == (it-1)&1
      const u64 want = ((it - 1) & 1) ? PM : 0ull;
      bool ok = true;
#pragma unroll
      for (int i = 0; i < 8; ++i) ok &= ((hv[i] & PM) == want);
      int bud = 1 << 13;
      while (!ok && --bud) {
#pragma unroll
        for (int i = 0; i < 8; ++i)
          hv[i] = __hip_atomic_load(hb8[i], __ATOMIC_RELAXED, __HIP_MEMORY_SCOPE_AGENT);
        ok = true;
#pragma unroll
        for (int i = 0; i < 8; ++i) ok &= ((hv[i] & PM) == want);
      }
      bf16x8 ha[4];
#pragma unroll
      for (int kt = 0; kt < 4; ++kt) {
        union { u64 q[2]; bf16x8 v; } cv;
        cv.q[0] = hv[kt * 2]; cv.q[1] = hv[kt * 2 + 1];
        ha[kt] = cv.v;
      }
#pragma unroll
      for (int gg = 0; gg < 4; ++gg)
#pragma unroll
        for (int kt = 0; kt < 4; ++kt)
          accg[gg] = __builtin_amdgcn_mfma_f32_16x16x32_bf16(ha[kt], whh_f[gg * 4 + kt], accg[gg], 0, 0, 0);
    }
    // partials -> LDS, one ds_write_b128 per gate (layout [wv][g][kh][lm][rr])
#pragma unroll
    for (int gg = 0; gg < 4; ++gg)
      *(f32x4*)&pre4[wv * 1024 + gg * 256 + kh * 64 + lm * 4] = accg[gg];
    __syncthreads();
    const int off = (bl >> 2) * 64 + jj * 4 + (bl & 3);
    float pi = b_i, pf = b_f, pg = b_g, po = b_o;
#pragma unroll
    for (int w = 0; w < 4; ++w) {
      pi += pre4[w * 1024 + 0   + off];
      pf += pre4[w * 1024 + 256 + off];
      pg += pre4[w * 1024 + 512 + off];
      po += pre4[w * 1024 + 768 + off];
    }
    c = sigm(pf) * c + sigm(pi) * tanh_f(pg);
    const float h = sigm(po) * tanh_f(c);
    const float hq = __shfl_xor(h, 1);
    if ((tid & 1) == 0) {   // pack pair -> u32, force LSB = it&1, agent store
      const u32 p = (u32)(it & 1);
      const u32 lo = ((u32)f2b(h) & 0xFFFEu) | p;
      const u32 hi = ((u32)f2b(hq) & 0xFFFEu) | p;
      const u32 pk = lo | (hi << 16);
      u32* hp2 = (u32*)H2 + ((((size_t)tt * 2 + d) * 4 + g) * 32 + s) * 128 + (tid >> 1);
      __hip_atomic_store(hp2, pk, __ATOMIC_RELAXED, __HIP_MEMORY_SCOPE_AGENT);
    }
    __syncthreads();   // pre4 reuse guard (next iter's ds_write)
  }
}

// ---------------------------------------------------------------------------
// em[t*64+b][tag] = [hf|hb] @ W_out^T + b_out. One block per t; blocked-H2 A.
__global__ __launch_bounds__(256) void k_emproj(
    const u16* __restrict__ H2, const float* __restrict__ Wo,
    const float* __restrict__ bo, float* __restrict__ em) {
  __shared__ u16 Wl[32 * 1024];
  const int tid = threadIdx.x, mb = blockIdx.x;
  const int wv = tid >> 6, lane = tid & 63, lm = lane & 15, kh = lane >> 4;
#pragma unroll
  for (int i = 0; i < 32; ++i) {        // stage Wo 32x1024 f32 -> bf16, rotated
    const int row = i, k = tid * 4;
    const float4 f = *(const float4*)(Wo + (size_t)row * 1024 + k);
    ushort4 s; s.x = f2b(f.x); s.y = f2b(f.y); s.z = f2b(f.z); s.w = f2b(f.w);
    *(ushort4*)&Wl[row * 1024 + ((k + 8 * row) & 1023)] = s;
  }
  __syncthreads();
  const f32x4 z = {0.f, 0.f, 0.f, 0.f};
  f32x4 acc[2] = {z, z};
#pragma unroll 2
  for (int kt = 0; kt < 32; ++kt) {     // k-global = kt*32 + kh*8 + j
    const int dd = kt >> 4;
    const int sG = (kt & 15) * 2 + (kh >> 1);
    const u16* ap = H2 + ((((size_t)mb * 2 + dd) * 4 + wv) * 32 + sG) * 256 + lm * 16 + (kh & 1) * 8;
    const bf16x8 a = *(const bf16x8*)ap;
#pragma unroll
    for (int ni = 0; ni < 2; ++ni) {
      const int row = ni * 16 + lm;
      const bf16x8 b = *(const bf16x8*)&Wl[row * 1024 + ((kt * 32 + kh * 8 + 8 * row) & 1023)];
      acc[ni] = __builtin_amdgcn_mfma_f32_16x16x32_bf16(a, b, acc[ni], 0, 0, 0);
    }
  }
#pragma unroll
  for (int ni = 0; ni < 2; ++ni) {
    const int n = ni * 16 + lm;
    const float bv = bo[n];
#pragma unroll
    for (int rr = 0; rr < 4; ++rr) {
      const int m = mb * 64 + wv * 16 + kh * 4 + rr;
      em[(size_t)m * 32 + n] = acc[ni][rr] + bv;
    }
  }
}

// ---------------------------------------------------------------------------
// CRF forward scans, fp32. One wave per (b, which); halves merged via
// shfl_xor(32); t+1 prefetch; final reduction via atomicAdd(out).
__global__ __launch_bounds__(64) void k_crf(
    const float* __restrict__ em, const int* __restrict__ tgt,
    const float* __restrict__ trans, const float* __restrict__ stt,
    const float* __restrict__ ent, float* __restrict__ out) {
  __shared__ float trl[1024];
  __shared__ float al[32];
  __shared__ int cur[32];
  const int lane = threadIdx.x;
  const int b = blockIdx.x >> 1;
  const int isnum = blockIdx.x & 1;
#pragma unroll
  for (int i = 0; i < 16; ++i) trl[i * 64 + lane] = trans[i * 64 + lane];
  const int k = lane & 31, j0 = (lane >> 5) * 16;
  {
    float a0 = stt[k] + em[(size_t)b * 32 + k];
    int p0 = 1;
    if (isnum) { p0 = tgt[((size_t)b * 512) * 32 + k]; if (p0 == 0) a0 = IMPOSSIBLE; }
    if (lane < 32) { al[k] = a0; cur[k] = p0; }
  }
  __syncthreads();
  float emk = em[((size_t)64 + b) * 32 + k];                    // t=1 prefetch
  int tg = isnum ? tgt[((size_t)b * 512 + 1) * 32 + k] : 1;
#pragma unroll 1
  for (int t = 1; t < 512; ++t) {
    const float e_raw = emk;
    const int nxt = tg;
    if (t + 1 < 512) {                                          // prefetch t+1
      emk = em[((size_t)(t + 1) * 64 + b) * 32 + k];
      if (isnum) tg = tgt[((size_t)b * 512 + t + 1) * 32 + k];
    }
    const float e = (isnum && nxt == 0) ? IMPOSSIBLE : e_raw;
    float v[16];
    float m = -1e30f;
#pragma unroll
    for (int j = 0; j < 16; ++j) {
      float tr = trl[(j0 + j) * 32 + k];
      if (isnum && (cur[j0 + j] == 0 || nxt == 0)) tr = IMPOSSIBLE;
      v[j] = al[j0 + j] + tr;
      m = fmaxf(m, v[j]);
    }
    float ss = 0.f;
#pragma unroll
    for (int j = 0; j < 16; ++j) ss += __expf(v[j] - m);
    const float m2 = __shfl_xor(m, 32);
    const float s2 = __shfl_xor(ss, 32);
    const float M = fmaxf(m, m2);
    const float S = ss * __expf(m - M) + s2 * __expf(m2 - M);
    const float an = M + __logf(S) + e;
    __syncthreads();
    if (lane < 32) { al[k] = an; cur[k] = nxt; }
    __syncthreads();
  }
  float x;
  if (!isnum) {
    x = al[k] + ent[k];
  } else {
    const float et = ent[k] * (float)cur[k];
    x = al[k] + ((et == 0.f) ? IMPOSSIBLE : et);
  }
  float m = x;
#pragma unroll
  for (int o = 1; o < 32; o <<= 1) m = fmaxf(m, __shfl_xor(m, o));
  float ss = __expf(x - m);
#pragma unroll
  for (int o = 1; o < 32; o <<= 1) ss += __shfl_xor(ss, o);
  if (lane == 0) {
    const float rr = m + __logf(ss);
    atomicAdd(out, isnum ? -rr : rr);
  }
}

// ---------------------------------------------------------------------------
extern "C" void kernel_launch(void* const* d_in, const int* in_sizes, int n_in,
                              void* d_out, int out_size, void* d_ws, size_t ws_size,
                              hipStream_t stream) {
  (void)in_sizes; (void)n_in; (void)out_size; (void)ws_size;
  const int* sents = (const int*)d_in[0];
  const int* tgt = (const int*)d_in[2];
  const float* emb = (const float*)d_in[3];
  const float* Wif = (const float*)d_in[4];
  const float* Whf = (const float*)d_in[5];
  const float* bf_ = (const float*)d_in[6];
  const float* Wib = (const float*)d_in[7];
  const float* Whb = (const float*)d_in[8];
  const float* bb_ = (const float*)d_in[9];
  const float* Wo = (const float*)d_in[10];
  const float* bo = (const float*)d_in[11];
  const float* stt = (const float*)d_in[12];
  const float* ent = (const float*)d_in[13];
  const float* trans = (const float*)d_in[14];
  float* out = (float*)d_out;

  char* ws = (char*)d_ws;
  u16* x2 = (u16*)ws;                          // 16777216 B
  u16* H2 = (u16*)(ws + 16777216ull);          // 67108864 B (blocked)
  float* em = (float*)(ws + 83886080ull);      //  4194304 B

  k_init<<<dim3(1), dim3(64), 0, stream>>>(out);
  k_fill<<<dim3(8192), dim3(256), 0, stream>>>((u64*)H2);
  k_embed<<<dim3(512), dim3(256), 0, stream>>>(sents, emb, x2);
  k_lstm<<<dim3(256), dim3(256), 0, stream>>>(Whf, Whb, Wif, Wib, bf_, bb_, x2, H2);
  k_emproj<<<dim3(512), dim3(256), 0, stream>>>(H2, Wo, bo, em);
  k_crf<<<dim3(128), dim3(64), 0, stream>>>(em, tgt, trans, stt, ent, out);
}